// Round 7
// baseline (222.251 us; speedup 1.0000x reference)
//
#include <hip/hip_runtime.h>
#include <hip/hip_cooperative_groups.h>

#define N 4096
#define IN_F 256
#define OUT_F 64
#define HEADS 4
#define ALPHA 0.2f
#define SEG 64    // max hits per quarter-row segment (mean ~5.1; >25 sigma margin)

typedef __attribute__((ext_vector_type(8))) short short8;
typedef __attribute__((ext_vector_type(4))) float f32x4;

__device__ __forceinline__ unsigned short f2bf(float f) {
    unsigned u = __builtin_bit_cast(unsigned, f);
    u += 0x7fffu + ((u >> 16) & 1u);            // round-to-nearest-even
    return (unsigned short)(u >> 16);
}

// ---------------------------------------------------------------------------
// Single cooperative kernel: phase 0 hamT build | phase 1 MFMA GEMM + e-dots
// | phase 2 fused masked-softmax attention (4 rows per block).
// Grid = 1024 blocks x 256 threads, all co-resident (4 blocks/CU).
// ---------------------------------------------------------------------------
__global__ __launch_bounds__(256, 4) void k_fused(
        const float* __restrict__ x, const float* __restrict__ adj,
        const float* __restrict__ W, const float* __restrict__ a,
        float* __restrict__ out,
        unsigned short* __restrict__ hamT, float* __restrict__ h,
        float* __restrict__ esp, float* __restrict__ edp) {
    cooperative_groups::grid_group grid = cooperative_groups::this_grid();
    const int wave = threadIdx.x >> 6, lane = threadIdx.x & 63;

    // ================= phase 0: hamT[hd][f][k] (bf16, k contiguous) ========
    const int gtid = blockIdx.x * 256 + threadIdx.x;
    if (gtid < HEADS * OUT_F * IN_F) {                    // 65536
        const int hd = gtid >> 14, f = (gtid >> 8) & 63, k = gtid & 255;
        const int q = k >> 6, kr = k & 63, p = f >> 4, fr = f & 15;
        const int   comp_t[4][4] = {{0,1,2,3},{1,0,3,2},{2,3,0,1},{3,2,1,0}};
        const float sign_t[4][4] = {{1.f,-1.f,-1.f,-1.f},
                                    {1.f, 1.f,-1.f, 1.f},
                                    {1.f, 1.f, 1.f,-1.f},
                                    {1.f,-1.f, 1.f, 1.f}};
        hamT[gtid] = f2bf(sign_t[q][p] * W[(hd * 64 + kr) * 64 + comp_t[q][p] * 16 + fr]);
    }
    grid.sync();

    // ================= phase 1: h = x @ ham via bf16 MFMA ===================
    // 2048 wave-tasks over 4096 waves (even gw active -> 2 active waves/block,
    // uniform across CUs). One task = 16 rows x 32 cols (half a head).
    const int gw = blockIdx.x * 4 + wave;
    if ((gw & 1) == 0) {
        const int task = gw >> 1;                 // 0..2047
        const int rg = task >> 3;                 // 16-row group
        const int hd = (task >> 1) & 3;
        const int cf = task & 1;                  // column half
        const int m0 = rg * 16;
        const int r16 = lane & 15, g = lane >> 4;

        // A fragments straight from fp32 x, cast in-register
        const float* xrow = x + (size_t)(m0 + r16) * IN_F + g * 8;
        short8 af[8];
#pragma unroll
        for (int kk = 0; kk < 8; ++kk) {
            const float4 u0 = *reinterpret_cast<const float4*>(xrow + kk * 32);
            const float4 u1 = *reinterpret_cast<const float4*>(xrow + kk * 32 + 4);
            short8 t;
            t[0] = (short)f2bf(u0.x); t[1] = (short)f2bf(u0.y);
            t[2] = (short)f2bf(u0.z); t[3] = (short)f2bf(u0.w);
            t[4] = (short)f2bf(u1.x); t[5] = (short)f2bf(u1.y);
            t[6] = (short)f2bf(u1.z); t[7] = (short)f2bf(u1.w);
            af[kk] = t;
        }

        f32x4 acc[2];
#pragma unroll
        for (int t = 0; t < 2; ++t) acc[t] = (f32x4){0.f, 0.f, 0.f, 0.f};

        const unsigned short* hbase = hamT + (size_t)(hd * 64 + cf * 32 + r16) * IN_F + g * 8;
#pragma unroll
        for (int kk = 0; kk < 8; ++kk) {
#pragma unroll
            for (int t = 0; t < 2; ++t) {
                const short8 bf = *reinterpret_cast<const short8*>(hbase + t * 16 * IN_F + kk * 32);
                acc[t] = __builtin_amdgcn_mfma_f32_16x16x32_bf16(af[kk], bf, acc[t], 0, 0, 0);
            }
        }

        // D layout: acc[t][j] at (row = m0+g*4+j, col f = cf*32 + t*16 + r16)
        float p[4] = {0.f, 0.f, 0.f, 0.f}, q[4] = {0.f, 0.f, 0.f, 0.f};
#pragma unroll
        for (int t = 0; t < 2; ++t) {
            const int fcol = cf * 32 + t * 16 + r16;
            const float as = a[hd * 128 + fcol];
            const float ad = a[hd * 128 + 64 + fcol];
#pragma unroll
            for (int j = 0; j < 4; ++j) {
                const float v = acc[t][j];
                h[(size_t)(m0 + g * 4 + j) * (HEADS * OUT_F) + hd * 64 + fcol] = v;
                p[j] = fmaf(v, as, p[j]);
                q[j] = fmaf(v, ad, q[j]);
            }
        }
#pragma unroll
        for (int off = 1; off < 16; off <<= 1) {
#pragma unroll
            for (int j = 0; j < 4; ++j) {
                p[j] += __shfl_xor(p[j], off);
                q[j] += __shfl_xor(q[j], off);
            }
        }
        if (r16 == 0) {
#pragma unroll
            for (int j = 0; j < 4; ++j) {
                const int row = m0 + g * 4 + j;
                esp[row * 8 + hd * 2 + cf] = p[j];
                edp[row * 8 + hd * 2 + cf] = q[j];
            }
        }
    }
    grid.sync();

    // ================= phase 2: attention, 4 rows per block =================
    __shared__ int   s_seg[4][SEG];
    __shared__ int   s_cnt[4];
    __shared__ int   s_all[4 * SEG];
    __shared__ float s_z[4][4 * SEG];

    const unsigned long long lmask_lt = (lane == 63) ? ~0ull >> 1
                                                     : (1ull << lane) - 1ull;
    for (int it = 0; it < 4; ++it) {
        const int i = it * 1024 + blockIdx.x;

        // ---- compaction: each wave scans its quarter row ----
        const uint4* arow = reinterpret_cast<const uint4*>(adj + (size_t)i * N) + wave * 256;
        uint4 av[4];
#pragma unroll
        for (int c = 0; c < 4; ++c) av[c] = arow[c * 64 + lane];

        int base = 0;
#pragma unroll
        for (int c = 0; c < 4; ++c) {
#pragma unroll
            for (int s = 0; s < 4; ++s) {
                const unsigned v = (s == 0) ? av[c].x : (s == 1) ? av[c].y
                                 : (s == 2) ? av[c].z : av[c].w;
                const bool hit = v != 0u;        // adj entries are exactly 0/1
                const unsigned long long mk = __ballot(hit);
                if (hit) {
                    const int pos = base + __popcll(mk & lmask_lt);
                    if (pos < SEG)
                        s_seg[wave][pos] = wave * 1024 + c * 256 + lane * 4 + s;
                }
                base += __popcll(mk);
            }
        }
        if (lane == 0) s_cnt[wave] = base < SEG ? base : SEG;
        __syncthreads();

        // merge segments (deterministic order)
        const int c0 = s_cnt[0], c1 = s_cnt[1], c2 = s_cnt[2], c3 = s_cnt[3];
        const int wbase = (wave > 0 ? c0 : 0) + (wave > 1 ? c1 : 0) + (wave > 2 ? c2 : 0);
        const int wcnt = s_cnt[wave];
        if (lane < wcnt) s_all[wbase + lane] = s_seg[wave][lane];
        __syncthreads();
        const int cnt = c0 + c1 + c2 + c3;

        // ---- exact per-row masked max (wave == head), z cached in LDS ----
        const int hd = wave;
        const float es = esp[i * 8 + hd * 2] + esp[i * 8 + hd * 2 + 1];
        float mh = -3.0e38f;
        for (int e = lane; e < cnt; e += 64) {
            const int j = s_all[e];
            const float ed = edp[j * 8 + hd * 2] + edp[j * 8 + hd * 2 + 1];
            float z = es + ed;
            z = z > 0.f ? z : ALPHA * z;
            s_z[hd][e] = z;
            mh = fmaxf(mh, z);
        }
#pragma unroll
        for (int off = 32; off > 0; off >>= 1) mh = fmaxf(mh, __shfl_xor(mh, off));

        // ---- accumulate: thread = (head, feature) ----
        float lsum = 0.f, acc = 0.f;
        int e = 0;
        for (; e + 4 <= cnt; e += 4) {
            const int j0 = s_all[e], j1 = s_all[e + 1], j2 = s_all[e + 2], j3 = s_all[e + 3];
            const float h0 = h[(size_t)j0 * 256 + threadIdx.x];
            const float h1 = h[(size_t)j1 * 256 + threadIdx.x];
            const float h2 = h[(size_t)j2 * 256 + threadIdx.x];
            const float h3 = h[(size_t)j3 * 256 + threadIdx.x];
            const float w0 = __expf(s_z[hd][e]     - mh);
            const float w1 = __expf(s_z[hd][e + 1] - mh);
            const float w2 = __expf(s_z[hd][e + 2] - mh);
            const float w3 = __expf(s_z[hd][e + 3] - mh);
            lsum += w0 + w1 + w2 + w3;
            acc = fmaf(w0, h0, acc);
            acc = fmaf(w1, h1, acc);
            acc = fmaf(w2, h2, acc);
            acc = fmaf(w3, h3, acc);
        }
        for (; e < cnt; ++e) {
            const int j = s_all[e];
            const float hv = h[(size_t)j * 256 + threadIdx.x];
            const float w = __expf(s_z[hd][e] - mh);
            lsum += w;
            acc = fmaf(w, hv, acc);
        }

        const float v = acc / lsum;
        out[(size_t)i * 256 + threadIdx.x] = v > 0.f ? v : __expf(v) - 1.f;
    }
}

// ---------------------------------------------------------------------------
extern "C" void kernel_launch(void* const* d_in, const int* in_sizes, int n_in,
                              void* d_out, int out_size, void* d_ws, size_t ws_size,
                              hipStream_t stream) {
    const float* x   = (const float*)d_in[0];
    const float* adj = (const float*)d_in[1];
    const float* W   = (const float*)d_in[2];
    const float* a   = (const float*)d_in[3];
    float* out = (float*)d_out;

    float* ws  = (float*)d_ws;
    float* h   = ws;                           // 4096*256 = 1048576 floats
    float* esp = h + (size_t)N * 256;          // 32768
    float* edp = esp + N * 8;                  // 32768
    unsigned short* hamT = (unsigned short*)(edp + N * 8);  // 65536 bf16

    void* args[] = {(void*)&x, (void*)&adj, (void*)&W, (void*)&a,
                    (void*)&out, (void*)&hamT, (void*)&h, (void*)&esp, (void*)&edp};
    hipLaunchCooperativeKernel((void*)k_fused, dim3(1024), dim3(256),
                               args, 0, stream);
}

// Round 8
// 39.496 us; speedup vs baseline: 5.6272x; 5.6272x over previous
//
#include <hip/hip_runtime.h>

#define N 4096
#define IN_F 256
#define OUT_F 64
#define HEADS 4
#define ALPHA 0.2f
#define SEG 64    // max hits per quarter-row segment (mean ~5.1; >25 sigma margin)

typedef __attribute__((ext_vector_type(8))) short short8;
typedef __attribute__((ext_vector_type(4))) float f32x4;

__device__ __forceinline__ unsigned short f2bf(float f) {
    unsigned u = __builtin_bit_cast(unsigned, f);
    u += 0x7fffu + ((u >> 16) & 1u);            // round-to-nearest-even
    return (unsigned short)(u >> 16);
}

__device__ __forceinline__ float bf2f(unsigned short u) {
    return __builtin_bit_cast(float, (unsigned)u << 16);
}

// ---------------------------------------------------------------------------
// K1: cast x -> bf16 AND build transposed bf16 hamilton hamT[hd][f][k].
// ---------------------------------------------------------------------------
__global__ __launch_bounds__(256) void k_prep(const float* __restrict__ x,
                                              const float* __restrict__ W,
                                              unsigned short* __restrict__ xb,
                                              unsigned short* __restrict__ hamT) {
    const int tid = blockIdx.x * 256 + threadIdx.x;      // 262144 threads
    const float4 xv = *reinterpret_cast<const float4*>(x + (size_t)tid * 4);
    ushort4 o;
    o.x = f2bf(xv.x); o.y = f2bf(xv.y); o.z = f2bf(xv.z); o.w = f2bf(xv.w);
    *reinterpret_cast<ushort4*>(xb + (size_t)tid * 4) = o;

    if (tid < HEADS * OUT_F * IN_F) {                    // 65536
        const int hd = tid >> 14, f = (tid >> 8) & 63, k = tid & 255;
        const int q = k >> 6, kr = k & 63, p = f >> 4, fr = f & 15;
        const int   comp_t[4][4] = {{0,1,2,3},{1,0,3,2},{2,3,0,1},{3,2,1,0}};
        const float sign_t[4][4] = {{1.f,-1.f,-1.f,-1.f},
                                    {1.f, 1.f,-1.f, 1.f},
                                    {1.f, 1.f, 1.f,-1.f},
                                    {1.f,-1.f, 1.f, 1.f}};
        hamT[tid] = f2bf(sign_t[q][p] * W[(hd * 64 + kr) * 64 + comp_t[q][p] * 16 + fr]);
    }
}

// ---------------------------------------------------------------------------
// K2: h = x @ ham via bf16 MFMA. One wave = 16 rows x HALF a head (32 cols).
// h is stored as BF16 (2 MB -> resident in every XCD L2 for the gather).
// e_src/e_dst written as per-half partials esp/edp[row][hd][cf] (fp32, exact
// from fp32 accumulators; deterministic).
// ---------------------------------------------------------------------------
__global__ __launch_bounds__(256) void k_h(const unsigned short* __restrict__ xb,
                                           const unsigned short* __restrict__ hamT,
                                           const float* __restrict__ a,
                                           unsigned short* __restrict__ hb,
                                           float* __restrict__ esp,
                                           float* __restrict__ edp) {
    const int wave = threadIdx.x >> 6, lane = threadIdx.x & 63;
    const int gw = blockIdx.x * 4 + wave;     // 0..2047
    const int rg = gw >> 3;                   // 0..255  (16-row group)
    const int hd = (gw >> 1) & 3;
    const int cf = gw & 1;                    // column half
    const int m0 = rg * 16;
    const int r16 = lane & 15, g = lane >> 4;

    const unsigned short* xrow = xb + (size_t)(m0 + r16) * IN_F + g * 8;
    short8 af[8];
#pragma unroll
    for (int kk = 0; kk < 8; ++kk)
        af[kk] = *reinterpret_cast<const short8*>(xrow + kk * 32);

    f32x4 acc[2];
#pragma unroll
    for (int t = 0; t < 2; ++t) acc[t] = (f32x4){0.f, 0.f, 0.f, 0.f};

    const unsigned short* hbase = hamT + (size_t)(hd * 64 + cf * 32 + r16) * IN_F + g * 8;
#pragma unroll
    for (int kk = 0; kk < 8; ++kk) {
#pragma unroll
        for (int t = 0; t < 2; ++t) {
            const short8 bf = *reinterpret_cast<const short8*>(hbase + t * 16 * IN_F + kk * 32);
            acc[t] = __builtin_amdgcn_mfma_f32_16x16x32_bf16(af[kk], bf, acc[t], 0, 0, 0);
        }
    }

    // D layout: acc[t][j] at (row = m0 + g*4 + j, col f = cf*32 + t*16 + r16)
    float p[4] = {0.f, 0.f, 0.f, 0.f}, q[4] = {0.f, 0.f, 0.f, 0.f};
#pragma unroll
    for (int t = 0; t < 2; ++t) {
        const int fcol = cf * 32 + t * 16 + r16;
        const float as = a[hd * 128 + fcol];
        const float ad = a[hd * 128 + 64 + fcol];
#pragma unroll
        for (int j = 0; j < 4; ++j) {
            const float v = acc[t][j];
            hb[(size_t)(m0 + g * 4 + j) * (HEADS * OUT_F) + hd * 64 + fcol] = f2bf(v);
            p[j] = fmaf(v, as, p[j]);
            q[j] = fmaf(v, ad, q[j]);
        }
    }
#pragma unroll
    for (int off = 1; off < 16; off <<= 1) {
#pragma unroll
        for (int j = 0; j < 4; ++j) {
            p[j] += __shfl_xor(p[j], off);
            q[j] += __shfl_xor(q[j], off);
        }
    }
    if (r16 == 0) {
#pragma unroll
        for (int j = 0; j < 4; ++j) {
            const int row = m0 + g * 4 + j;
            esp[row * 8 + hd * 2 + cf] = p[j];
            edp[row * 8 + hd * 2 + cf] = q[j];
        }
    }
}

// ---------------------------------------------------------------------------
// K3: fused masked-softmax attention. ONE BLOCK PER ROW.
// Phase 1: each wave ballot-compacts its quarter row -> merged LDS edge list.
// Phase 1.5: wave == head; exact per-row masked max, z cached in LDS.
// Phase 2: thread = (head, feature); unroll-4 pipelined BF16 h gather.
// ---------------------------------------------------------------------------
__global__ __launch_bounds__(256) void k_attn(const float* __restrict__ adj,
                                              const unsigned short* __restrict__ hb,
                                              const float* __restrict__ esp,
                                              const float* __restrict__ edp,
                                              float* __restrict__ out) {
    __shared__ int   s_seg[4][SEG];
    __shared__ int   s_cnt[4];
    __shared__ int   s_all[4 * SEG];
    __shared__ float s_z[4][4 * SEG];

    const int wave = threadIdx.x >> 6;
    const int lane = threadIdx.x & 63;
    const int i = blockIdx.x;

    // ---- phase 1: per-wave quarter-row compaction ----
    const uint4* arow = reinterpret_cast<const uint4*>(adj + (size_t)i * N) + wave * 256;
    uint4 av[4];
#pragma unroll
    for (int c = 0; c < 4; ++c) av[c] = arow[c * 64 + lane];

    const unsigned long long lmask_lt = (lane == 63) ? ~0ull >> 1
                                                     : (1ull << lane) - 1ull;
    int base = 0;
#pragma unroll
    for (int c = 0; c < 4; ++c) {
#pragma unroll
        for (int s = 0; s < 4; ++s) {
            const unsigned v = (s == 0) ? av[c].x : (s == 1) ? av[c].y
                             : (s == 2) ? av[c].z : av[c].w;
            const bool hit = v != 0u;            // adj entries are exactly 0/1
            const unsigned long long mk = __ballot(hit);
            if (hit) {
                const int pos = base + __popcll(mk & lmask_lt);
                if (pos < SEG)
                    s_seg[wave][pos] = wave * 1024 + c * 256 + lane * 4 + s;
            }
            base += __popcll(mk);
        }
    }
    if (lane == 0) s_cnt[wave] = base < SEG ? base : SEG;
    __syncthreads();

    // merge segments into one contiguous list (deterministic order)
    const int c0 = s_cnt[0], c1 = s_cnt[1], c2 = s_cnt[2], c3 = s_cnt[3];
    const int wbase = (wave > 0 ? c0 : 0) + (wave > 1 ? c1 : 0) + (wave > 2 ? c2 : 0);
    const int wcnt = s_cnt[wave];
    if (lane < wcnt) s_all[wbase + lane] = s_seg[wave][lane];
    __syncthreads();
    const int cnt = c0 + c1 + c2 + c3;

    // ---- phase 1.5: exact per-row masked max (wave == head) ----
    const int hd = wave;
    const float es = esp[i * 8 + hd * 2] + esp[i * 8 + hd * 2 + 1];
    float mh = -3.0e38f;
    for (int e = lane; e < cnt; e += 64) {
        const int j = s_all[e];
        const float ed = edp[j * 8 + hd * 2] + edp[j * 8 + hd * 2 + 1];
        float z = es + ed;
        z = z > 0.f ? z : ALPHA * z;
        s_z[hd][e] = z;
        mh = fmaxf(mh, z);
    }
#pragma unroll
    for (int off = 32; off > 0; off >>= 1) mh = fmaxf(mh, __shfl_xor(mh, off));

    // ---- phase 2: thread = (head, feature); bf16 h gather ----
    float lsum = 0.f, acc = 0.f;
    int e = 0;
    for (; e + 4 <= cnt; e += 4) {
        const int j0 = s_all[e], j1 = s_all[e + 1], j2 = s_all[e + 2], j3 = s_all[e + 3];
        const unsigned short u0 = hb[(size_t)j0 * 256 + threadIdx.x];
        const unsigned short u1 = hb[(size_t)j1 * 256 + threadIdx.x];
        const unsigned short u2 = hb[(size_t)j2 * 256 + threadIdx.x];
        const unsigned short u3 = hb[(size_t)j3 * 256 + threadIdx.x];
        const float w0 = __expf(s_z[hd][e]     - mh);
        const float w1 = __expf(s_z[hd][e + 1] - mh);
        const float w2 = __expf(s_z[hd][e + 2] - mh);
        const float w3 = __expf(s_z[hd][e + 3] - mh);
        lsum += w0 + w1 + w2 + w3;
        acc = fmaf(w0, bf2f(u0), acc);
        acc = fmaf(w1, bf2f(u1), acc);
        acc = fmaf(w2, bf2f(u2), acc);
        acc = fmaf(w3, bf2f(u3), acc);
    }
    for (; e < cnt; ++e) {
        const int j = s_all[e];
        const unsigned short u = hb[(size_t)j * 256 + threadIdx.x];
        const float w = __expf(s_z[hd][e] - mh);
        lsum += w;
        acc = fmaf(w, bf2f(u), acc);
    }

    const float v = acc / lsum;
    out[(size_t)i * 256 + threadIdx.x] = v > 0.f ? v : __expf(v) - 1.f;
}

// ---------------------------------------------------------------------------
extern "C" void kernel_launch(void* const* d_in, const int* in_sizes, int n_in,
                              void* d_out, int out_size, void* d_ws, size_t ws_size,
                              hipStream_t stream) {
    const float* x   = (const float*)d_in[0];
    const float* adj = (const float*)d_in[1];
    const float* W   = (const float*)d_in[2];
    const float* a   = (const float*)d_in[3];
    float* out = (float*)d_out;

    float* ws   = (float*)d_ws;
    float* esp  = ws;                          // 4096*8 = 32768 floats
    float* edp  = esp + N * 8;                 // 32768
    unsigned short* hb   = (unsigned short*)(edp + N * 8);  // 4096*256 bf16
    unsigned short* xb   = hb + (size_t)N * 256;            // 1048576 bf16
    unsigned short* hamT = xb + (size_t)N * IN_F;           // 65536 bf16

    k_prep<<<1024, 256, 0, stream>>>(x, W, xb, hamT);
    k_h<<<512, 256, 0, stream>>>(xb, hamT, a, hb, esp, edp);
    k_attn<<<N, 256, 0, stream>>>(adj, hb, esp, edp, out);
}